// Round 7
// baseline (365.494 us; speedup 1.0000x reference)
//
#include <hip/hip_runtime.h>
#include <hip/hip_bf16.h>

#define Bn 4
#define Cc 64
#define CQn 8
#define Hh 256
#define Ww 256
#define PLANE 65536

typedef unsigned short ushortT;
typedef __attribute__((ext_vector_type(8))) unsigned short us8;
typedef __attribute__((ext_vector_type(4))) unsigned short us4;
typedef __attribute__((ext_vector_type(8))) __bf16 bf16x8;
typedef __attribute__((ext_vector_type(4))) float f32x4;

__device__ inline ushortT f2bf(float f) {
    __hip_bfloat16 h = __float2bfloat16(f);
    return *(ushortT*)&h;
}
__device__ inline float bf2f(ushortT u) {
    return __uint_as_float((unsigned)u << 16);
}
union BF8U { us8 u; bf16x8 b; uint4 w; };
__device__ inline us8 zero_us8() {
    BF8U z; z.w.x = 0; z.w.y = 0; z.w.z = 0; z.w.w = 0; return z.u;
}

// ---------- Kernel 1a: axial depthwise conv + relu (bf16 out) ----------
__global__ __launch_bounds__(256) void dw_kernel(
    const float* __restrict__ x,
    const float* __restrict__ hw, const float* __restrict__ hb,
    const float* __restrict__ vw, const float* __restrict__ vb,
    ushortT* __restrict__ aout)
{
    int blk = blockIdx.x;
    int bc = blk >> 4;
    int ht = blk & 15;
    int h0 = ht * 16;
    int c = bc & 63;
    int tid = threadIdx.x;
    __shared__ float rows[20][260];
    const float* xp = x + (size_t)bc * PLANE;
    #pragma unroll
    for (int i = 0; i < 20; ++i) {
        int hr = h0 - 2 + i;
        rows[i][tid + 2] = (hr >= 0 && hr < Hh) ? xp[hr * Ww + tid] : 0.f;
    }
    if (tid < 20) {
        rows[tid][0] = 0.f; rows[tid][1] = 0.f;
        rows[tid][258] = 0.f; rows[tid][259] = 0.f;
    }
    __syncthreads();

    float hw0 = hw[c * 5 + 0], hw1 = hw[c * 5 + 1], hw2 = hw[c * 5 + 2],
          hw3 = hw[c * 5 + 3], hw4 = hw[c * 5 + 4];
    float vw0 = vw[c * 5 + 0], vw1 = vw[c * 5 + 1], vw2 = vw[c * 5 + 2],
          vw3 = vw[c * 5 + 3], vw4 = vw[c * 5 + 4];
    float bias = hb[c] + vb[c];

    ushortT* op = aout + (size_t)bc * PLANE + h0 * Ww + tid;
    #pragma unroll
    for (int r = 0; r < 16; ++r) {
        float hs = hw0 * rows[r + 2][tid]     + hw1 * rows[r + 2][tid + 1]
                 + hw2 * rows[r + 2][tid + 2] + hw3 * rows[r + 2][tid + 3]
                 + hw4 * rows[r + 2][tid + 4];
        float vs = vw0 * rows[r][tid + 2]     + vw1 * rows[r + 1][tid + 2]
                 + vw2 * rows[r + 2][tid + 2] + vw3 * rows[r + 3][tid + 2]
                 + vw4 * rows[r + 4][tid + 2];
        float res = hs + vs + bias + rows[r + 2][tid + 2];
        op[r * Ww] = f2bf(fmaxf(res, 0.f));
    }
}

// ---------- Kernel 1b: pointwise 64x64 via MFMA + fused stats partials ----------
__global__ __launch_bounds__(256) void pw_mfma_kernel(
    const ushortT* __restrict__ a_bf, const float* __restrict__ pwwf,
    const float* __restrict__ pwb,
    float* __restrict__ y_raw, float* __restrict__ sums, float* __restrict__ sumsq)
{
    int blk = blockIdx.x;
    int b = blk >> 8;
    int t0 = (blk & 255) << 8;
    int tid = threadIdx.x, lane = tid & 63, wv = tid >> 6;
    int half = lane >> 4;
    int col = lane & 15;

    __shared__ ushortT ytile[256 * 74];

    {
        size_t base = (size_t)b * Cc * PLANE + t0 + tid;
        uint* wrow = (uint*)&ytile[tid * 74];
        #pragma unroll
        for (int c = 0; c < Cc; c += 2) {
            ushortT v0 = a_bf[base + (size_t)c * PLANE];
            ushortT v1 = a_bf[base + (size_t)(c + 1) * PLANE];
            wrow[c >> 1] = (uint)v0 | ((uint)v1 << 16);
        }
    }
    __syncthreads();

    int m0 = wv * 16;
    BF8U a0, a1;
    {
        const float* wr = pwwf + (m0 + col) * 64 + half * 8;
        #pragma unroll
        for (int e = 0; e < 8; ++e) {
            a0.u[e] = f2bf(wr[e]);
            a1.u[e] = f2bf(wr[32 + e]);
        }
    }

    float bias[4], s[4], s2[4];
    #pragma unroll
    for (int r = 0; r < 4; ++r) {
        bias[r] = pwb[m0 + half * 4 + r];
        s[r] = 0.f; s2[r] = 0.f;
    }

    const uint* lw = (const uint*)ytile;
    #pragma unroll 4
    for (int t = 0; t < 16; ++t) {
        int rbase = (t * 16 + col) * 37 + half * 4;
        BF8U b0, b1;
        b0.w.x = lw[rbase];      b0.w.y = lw[rbase + 1];
        b0.w.z = lw[rbase + 2];  b0.w.w = lw[rbase + 3];
        b1.w.x = lw[rbase + 16]; b1.w.y = lw[rbase + 17];
        b1.w.z = lw[rbase + 18]; b1.w.w = lw[rbase + 19];
        f32x4 acc = (f32x4){0.f, 0.f, 0.f, 0.f};
        acc = __builtin_amdgcn_mfma_f32_16x16x32_bf16(a0.b, b0.b, acc, 0, 0, 0);
        acc = __builtin_amdgcn_mfma_f32_16x16x32_bf16(a1.b, b1.b, acc, 0, 0, 0);
        int pix = t * 16 + col;
        #pragma unroll
        for (int r = 0; r < 4; ++r) {
            int c = m0 + half * 4 + r;
            float v = acc[r] + bias[r];
            y_raw[(size_t)(b * Cc + c) * PLANE + t0 + pix] = v;
            s[r] += v; s2[r] += v * v;
        }
    }
    #pragma unroll
    for (int r = 0; r < 4; ++r) {
        #pragma unroll
        for (int d = 8; d > 0; d >>= 1) {
            s[r]  += __shfl_down(s[r], d, 16);
            s2[r] += __shfl_down(s2[r], d, 16);
        }
    }
    if (col == 0) {
        #pragma unroll
        for (int r = 0; r < 4; ++r) {
            int c = m0 + half * 4 + r;
            atomicAdd(&sums[b * Cc + c], s[r]);
            atomicAdd(&sumsq[b * Cc + c], s2[r]);
        }
    }
}

// ---------- Kernel 4: norm-fold + normalize + q/k/val projections via MFMA ----------
__global__ __launch_bounds__(256) void qkv_mfma_kernel(
    const float* __restrict__ y_raw,
    const float* __restrict__ sums, const float* __restrict__ sumsq,
    const float* __restrict__ bnw, const float* __restrict__ bnb,
    const float* __restrict__ qwf, const float* __restrict__ qbias,
    const float* __restrict__ kwf, const float* __restrict__ kbias,
    const float* __restrict__ vwf, const float* __restrict__ vbias,
    ushortT* __restrict__ q, ushortT* __restrict__ k,
    ushortT* __restrict__ val)
{
    int blk = blockIdx.x;
    int b = blk >> 8;
    int t0 = (blk & 255) << 8;
    int tid = threadIdx.x, lane = tid & 63, wv = tid >> 6;
    int half = lane >> 4;
    int col = lane & 15;

    __shared__ ushortT ytile[256 * 74];
    __shared__ float alpha_s[64], beta_s[64];

    if (tid < 64) {
        int c = tid;
        float im[4], e2[4];
        float bm = 0.f, be2 = 0.f;
        #pragma unroll
        for (int bb = 0; bb < 4; ++bb) {
            im[bb] = sums[bb * Cc + c] * (1.f / 65536.f);
            e2[bb] = sumsq[bb * Cc + c] * (1.f / 65536.f);
            bm += im[bb]; be2 += e2[bb];
        }
        bm *= 0.25f; be2 *= 0.25f;
        float rsb = rsqrtf(be2 - bm * bm + 1e-5f);
        float wgt = bnw[c];
        float rsi = rsqrtf(e2[b] - im[b] * im[b] + 1e-5f);
        alpha_s[c] = 0.7f * rsi + 0.3f * rsb * wgt;
        beta_s[c]  = -0.7f * im[b] * rsi - 0.3f * bm * rsb * wgt + 0.3f * bnb[c];
    }
    __syncthreads();

    {
        size_t base = (size_t)b * Cc * PLANE + t0 + tid;
        uint* wrow = (uint*)&ytile[tid * 74];
        #pragma unroll
        for (int c = 0; c < Cc; c += 2) {
            float v0 = y_raw[base + (size_t)c * PLANE];
            float v1 = y_raw[base + (size_t)(c + 1) * PLANE];
            float n0 = alpha_s[c] * v0 + beta_s[c];
            float n1 = alpha_s[c + 1] * v1 + beta_s[c + 1];
            wrow[c >> 1] = (uint)f2bf(n0) | ((uint)f2bf(n1) << 16);
        }
    }
    __syncthreads();

    const uint* lw = (const uint*)ytile;

    {
        // combined q/k projection: rows 0-7 = q, 8-15 = k
        const float* wr = (col < 8) ? (qwf + col * 64) : (kwf + (col - 8) * 64);
        BF8U a0, a1;
        #pragma unroll
        for (int e = 0; e < 8; ++e) {
            a0.u[e] = f2bf(wr[half * 8 + e]);
            a1.u[e] = f2bf(wr[32 + half * 8 + e]);
        }
        #pragma unroll
        for (int i = 0; i < 4; ++i) {
            int t = wv * 4 + i;
            int rbase = (t * 16 + col) * 37 + half * 4;
            BF8U b0, b1;
            b0.w.x = lw[rbase];      b0.w.y = lw[rbase + 1];
            b0.w.z = lw[rbase + 2];  b0.w.w = lw[rbase + 3];
            b1.w.x = lw[rbase + 16]; b1.w.y = lw[rbase + 17];
            b1.w.z = lw[rbase + 18]; b1.w.w = lw[rbase + 19];
            f32x4 acc = (f32x4){0.f, 0.f, 0.f, 0.f};
            acc = __builtin_amdgcn_mfma_f32_16x16x32_bf16(a0.b, b0.b, acc, 0, 0, 0);
            acc = __builtin_amdgcn_mfma_f32_16x16x32_bf16(a1.b, b1.b, acc, 0, 0, 0);
            int pix = t * 16 + col;
            #pragma unroll
            for (int r = 0; r < 4; ++r) {
                int row = half * 4 + r;
                if (row < 8)
                    q[(size_t)(b * CQn + row) * PLANE + t0 + pix] = f2bf(acc[r] + qbias[row]);
                else
                    k[(size_t)(b * CQn + row - 8) * PLANE + t0 + pix] = f2bf(acc[r] + kbias[row - 8]);
            }
        }
    }

    {
        int m0 = wv * 16;
        BF8U a0, a1;
        {
            const float* wr = vwf + (m0 + col) * 64 + half * 8;
            #pragma unroll
            for (int e = 0; e < 8; ++e) {
                a0.u[e] = f2bf(wr[e]);
                a1.u[e] = f2bf(wr[32 + e]);
            }
        }
        float bias[4];
        #pragma unroll
        for (int r = 0; r < 4; ++r) bias[r] = vbias[m0 + half * 4 + r];
        #pragma unroll 4
        for (int t = 0; t < 16; ++t) {
            int rbase = (t * 16 + col) * 37 + half * 4;
            BF8U b0, b1;
            b0.w.x = lw[rbase];      b0.w.y = lw[rbase + 1];
            b0.w.z = lw[rbase + 2];  b0.w.w = lw[rbase + 3];
            b1.w.x = lw[rbase + 16]; b1.w.y = lw[rbase + 17];
            b1.w.z = lw[rbase + 18]; b1.w.w = lw[rbase + 19];
            f32x4 acc = (f32x4){0.f, 0.f, 0.f, 0.f};
            acc = __builtin_amdgcn_mfma_f32_16x16x32_bf16(a0.b, b0.b, acc, 0, 0, 0);
            acc = __builtin_amdgcn_mfma_f32_16x16x32_bf16(a1.b, b1.b, acc, 0, 0, 0);
            int pix = t * 16 + col;
            #pragma unroll
            for (int r = 0; r < 4; ++r) {
                int c = m0 + half * 4 + r;
                val[(size_t)(b * Cc + c) * PLANE + t0 + pix] = f2bf(acc[r] + bias[r]);
            }
        }
    }
}

// ---------- Kernel 5: merged q/k/val plane transpose (one launch) ----------
__global__ __launch_bounds__(256) void transpose_all_kernel(
    const ushortT* __restrict__ qb, ushortT* __restrict__ qT,
    const ushortT* __restrict__ kb, ushortT* __restrict__ kT,
    const ushortT* __restrict__ vb, ushortT* __restrict__ vT)
{
    int blk = blockIdx.x;
    int plane = blk >> 6;
    int tile = blk & 63;
    const ushortT* src; ushortT* dst;
    if (plane < 32)      { src = qb + (size_t)plane * PLANE;        dst = qT + (size_t)plane * PLANE; }
    else if (plane < 64) { src = kb + (size_t)(plane - 32) * PLANE; dst = kT + (size_t)(plane - 32) * PLANE; }
    else                 { src = vb + (size_t)(plane - 64) * PLANE; dst = vT + (size_t)(plane - 64) * PLANE; }
    int th = (tile >> 3) * 32;
    int tw = (tile & 7) * 32;
    __shared__ ushortT t[32][34];
    int lw = threadIdx.x & 31;
    int lh = threadIdx.x >> 5;
    #pragma unroll
    for (int i = 0; i < 4; ++i)
        t[lh + 8 * i][lw] = src[(th + lh + 8 * i) * Ww + tw + lw];
    __syncthreads();
    #pragma unroll
    for (int i = 0; i < 4; ++i)
        dst[(tw + lh + 8 * i) * Hh + th + lw] = t[lw][lh + 8 * i];
}

// ---------- Kernel 6: TWO-PASS softmax attention (round-1 math + schedule) ----------
// A/B vs round 6: ONLY the exp/log flavor changes back to __expf/__logf (and q is
// no longer pre-scaled by log2e). Every exp2-builtin variant (r2/r4/r5/r6) stalled
// at 105-110us with identical MFMA-seconds; __expf variants hit the expected
// VALU-bound throughput. This isolates the hipcc lowering of the raw intrinsics.
__global__ __launch_bounds__(256) void attn_kernel(
    const ushortT* __restrict__ q0, const ushortT* __restrict__ k0,
    const ushortT* __restrict__ v0, ushortT* __restrict__ o0,
    const ushortT* __restrict__ q1, const ushortT* __restrict__ k1,
    const ushortT* __restrict__ v1, ushortT* __restrict__ o1)
{
    int blk = blockIdx.x;
    int sel = blk >> 10;
    const ushortT* __restrict__ q   = sel ? q1 : q0;
    const ushortT* __restrict__ k   = sel ? k1 : k0;
    const ushortT* __restrict__ val = sel ? v1 : v0;
    ushortT* __restrict__ outp      = sel ? o1 : o0;
    int bblk = blk & 1023;
    int b = bblk >> 8;
    int r = bblk & 255;
    int tid = threadIdx.x;
    int lane = tid & 63;
    int wv = tid >> 6;
    int col = lane & 15;
    int quad = lane >> 4;

    __shared__ ushortT q_s[256 * 8];        // [j][c] bf16
    __shared__ ushortT k_s[256 * 8];        // [i][c]
    __shared__ ushortT A_lds[4 * 256 * 8];  // [jq][i][8 bf16 j's]
    __shared__ float mhat[256];
    __shared__ float shiftv[256];
    __shared__ float kred[32];

    // ---- val row fragment for this lane: c = wv*16+col, j-slots quad*8..+8 ----
    size_t vbase = (size_t)b * Cc * PLANE + (size_t)r * Ww
                 + (size_t)(wv * 16 + col) * PLANE + quad * 8;
    BF8U afb[2];
    afb[0].u = *(const us8*)(val + vbase);   // slab 0, in flight through phase 1

    // ---- stage q,k ----
    size_t qkbase = (size_t)b * CQn * PLANE + (size_t)r * Ww + tid;
    float qf[8], ka[8];
    {
        BF8U qp, kp;
        #pragma unroll
        for (int c = 0; c < 8; ++c) {
            ushortT qv = q[qkbase + (size_t)c * PLANE];
            ushortT kv = k[qkbase + (size_t)c * PLANE];
            qp.u[c] = qv; kp.u[c] = kv;
            qf[c] = bf2f(qv);
            ka[c] = fabsf(bf2f(kv));
        }
        *(us8*)&q_s[tid * 8] = qp.u;
        *(us8*)&k_s[tid * 8] = kp.u;
    }
    #pragma unroll
    for (int d = 1; d < 64; d <<= 1)
        #pragma unroll
        for (int c = 0; c < 8; ++c)
            ka[c] = fmaxf(ka[c], __shfl_xor(ka[c], d));
    if (lane == 0)
        #pragma unroll
        for (int c = 0; c < 8; ++c) kred[wv * 8 + c] = ka[c];
    __syncthreads();

    // mhat[j] = sum_c |q_c| * kmax_c (safe upper bound on S row max)
    {
        float mh = 0.f;
        #pragma unroll
        for (int c = 0; c < 8; ++c) {
            float km = fmaxf(fmaxf(kred[c], kred[8 + c]),
                             fmaxf(kred[16 + c], kred[24 + c]));
            mh += fabsf(qf[c]) * km;
        }
        mhat[tid] = mh;
    }
    __syncthreads();

    // ---- phase 1: l[j] via MFMA sweep; shift = mhat + ln(l) ----
    #pragma unroll
    for (int t = 0; t < 4; ++t) {
        int jt = wv * 4 + t;
        BF8U qa; qa.u = zero_us8();
        if (quad == 0) qa.u = *(const us8*)&q_s[(jt * 16 + col) * 8];
        float mh4[4];
        #pragma unroll
        for (int rr = 0; rr < 4; ++rr) mh4[rr] = mhat[jt * 16 + quad * 4 + rr];
        f32x4 ls = (f32x4){0.f, 0.f, 0.f, 0.f};
        for (int it = 0; it < 16; ++it) {
            BF8U kb;
            kb.u = *(const us8*)&k_s[(it * 16 + col) * 8];  // unconditional, qa zeros k>=8
            f32x4 sacc = (f32x4){0.f, 0.f, 0.f, 0.f};
            sacc = __builtin_amdgcn_mfma_f32_16x16x32_bf16(qa.b, kb.b, sacc, 0, 0, 0);
            #pragma unroll
            for (int rr = 0; rr < 4; ++rr)
                ls[rr] += __expf(sacc[rr] - mh4[rr]);
        }
        #pragma unroll
        for (int d = 1; d < 16; d <<= 1)
            #pragma unroll
            for (int rr = 0; rr < 4; ++rr)
                ls[rr] += __shfl_xor(ls[rr], d);
        if (col == 0)
            #pragma unroll
            for (int rr = 0; rr < 4; ++rr)
                shiftv[jt * 16 + quad * 4 + rr] = mh4[rr] + __logf(ls[rr]);
    }
    __syncthreads();

    // ---- phase 2: per slab {E -> A_lds; barrier; AV; barrier} ----
    BF8U kc[4];
    #pragma unroll
    for (int i = 0; i < 4; ++i)
        kc[i].u = *(const us8*)&k_s[((wv * 4 + i) * 16 + col) * 8];
    f32x4 acc[16];
    #pragma unroll
    for (int t = 0; t < 16; ++t) acc[t] = (f32x4){0.f, 0.f, 0.f, 0.f};

    #pragma unroll
    for (int ks = 0; ks < 8; ++ks) {
        if (ks < 7)   // prefetch next val slab; hidden under E + barrier
            afb[(ks + 1) & 1].u = *(const us8*)(val + vbase + (ks + 1) * 32);
        #pragma unroll
        for (int jj2 = 0; jj2 < 2; ++jj2) {
            int jt = ks * 2 + jj2;
            BF8U qa; qa.u = zero_us8();
            if (quad == 0) qa.u = *(const us8*)&q_s[(jt * 16 + col) * 8];
            float sh4[4];
            #pragma unroll
            for (int rr = 0; rr < 4; ++rr) sh4[rr] = shiftv[jt * 16 + quad * 4 + rr];
            #pragma unroll
            for (int i = 0; i < 4; ++i) {
                f32x4 sacc = (f32x4){0.f, 0.f, 0.f, 0.f};
                sacc = __builtin_amdgcn_mfma_f32_16x16x32_bf16(qa.b, kc[i].b, sacc, 0, 0, 0);
                us4 pk;
                #pragma unroll
                for (int rr = 0; rr < 4; ++rr)
                    pk[rr] = f2bf(__expf(sacc[rr] - sh4[rr]));
                int irow = (wv * 4 + i) * 16 + col;
                int jq = jj2 * 2 + (quad >> 1);
                *(us4*)&A_lds[(jq * 256 + irow) * 8 + (quad & 1) * 4] = pk;
            }
        }
        __syncthreads();
        #pragma unroll
        for (int t = 0; t < 16; ++t) {
            BF8U bfr;
            bfr.u = *(const us8*)&A_lds[(quad * 256 + t * 16 + col) * 8];
            acc[t] = __builtin_amdgcn_mfma_f32_16x16x32_bf16(afb[ks & 1].b, bfr.b, acc[t], 0, 0, 0);
        }
        __syncthreads();
    }

    // store: C/D layout col=i, row c=quad*4+rr; wave wv owns c-tile wv
    size_t obase = (size_t)b * Cc * PLANE + (size_t)r * Ww;
    #pragma unroll
    for (int t = 0; t < 16; ++t) {
        int i = t * 16 + col;
        #pragma unroll
        for (int rr = 0; rr < 4; ++rr) {
            int c = wv * 16 + quad * 4 + rr;
            outp[obase + (size_t)c * PLANE + i] = f2bf(acc[t][rr]);
        }
    }
}

// ---------- Kernel 7: combine + residual + 2x2 maxpool ----------
__global__ __launch_bounds__(256) void final_kernel(
    const ushortT* __restrict__ houtT, const ushortT* __restrict__ hout0,
    const float* __restrict__ y_raw,
    const float* __restrict__ sums, const float* __restrict__ sumsq,
    const float* __restrict__ bnw, const float* __restrict__ bnb,
    const float* __restrict__ gamma,
    float* __restrict__ out, float* __restrict__ down)
{
    int blk = blockIdx.x;
    int tile = blk & 63;
    int bc = blk >> 6;
    int b = bc >> 6;
    int c = bc & 63;
    int th = (tile >> 3) * 32;
    int tw = (tile & 7) * 32;

    float im[4], e2[4];
    float bm = 0.f, be2 = 0.f;
    #pragma unroll
    for (int bb = 0; bb < 4; ++bb) {
        im[bb] = sums[bb * Cc + c] * (1.f / 65536.f);
        e2[bb] = sumsq[bb * Cc + c] * (1.f / 65536.f);
        bm += im[bb]; be2 += e2[bb];
    }
    bm *= 0.25f; be2 *= 0.25f;
    float rsb = rsqrtf(be2 - bm * bm + 1e-5f);
    float wgt = bnw[c];
    float rsi = rsqrtf(e2[b] - im[b] * im[b] + 1e-5f);
    float al = 0.7f * rsi + 0.3f * rsb * wgt;
    float bt = -0.7f * im[b] * rsi - 0.3f * bm * rsb * wgt + 0.3f * bnb[c];

    __shared__ float t[32][33];
    const ushortT* hT = houtT + (size_t)bc * PLANE;
    {
        int ww = threadIdx.x >> 3;
        int hh = (threadIdx.x & 7) * 4;
        us4 v4 = *(const us4*)(hT + (size_t)(tw + ww) * Hh + th + hh);
        t[hh + 0][ww] = __uint_as_float((unsigned)v4[0] << 16);
        t[hh + 1][ww] = __uint_as_float((unsigned)v4[1] << 16);
        t[hh + 2][ww] = __uint_as_float((unsigned)v4[2] << 16);
        t[hh + 3][ww] = __uint_as_float((unsigned)v4[3] << 16);
    }
    __syncthreads();
    float g = gamma[0];
    int qw_ = threadIdx.x & 15;
    int qh_ = threadIdx.x >> 4;
    const float* yb = y_raw + (size_t)bc * PLANE;
    const ushortT* hb = hout0 + (size_t)bc * PLANE;
    float* ob = out + (size_t)bc * PLANE;
    float mx = -1e30f;
    float2 res[2];
    #pragma unroll
    for (int i = 0; i < 2; ++i) {
        int hh = 2 * qh_ + i;
        int off = (th + hh) * Ww + tw + 2 * qw_;
        uint hv = *(const uint*)(hb + off);
        float2 y = *(const float2*)(yb + off);
        float y0 = al * y.x + bt;
        float y1 = al * y.y + bt;
        float o0 = g * (t[hh][2 * qw_]     + bf2f((ushortT)(hv & 0xffff))) + y0;
        float o1 = g * (t[hh][2 * qw_ + 1] + bf2f((ushortT)(hv >> 16)))   + y1;
        res[i] = make_float2(o0, o1);
        mx = fmaxf(mx, fmaxf(o0, o1));
    }
    #pragma unroll
    for (int i = 0; i < 2; ++i) {
        int off = (th + 2 * qh_ + i) * Ww + tw + 2 * qw_;
        *(float2*)(ob + off) = res[i];
    }
    down[(size_t)bc * 16384 + (th / 2 + qh_) * 128 + tw / 2 + qw_] = mx;
}

extern "C" void kernel_launch(void* const* d_in, const int* in_sizes, int n_in,
                              void* d_out, int out_size, void* d_ws, size_t ws_size,
                              hipStream_t stream)
{
    const float* x     = (const float*)d_in[0];
    const float* hw    = (const float*)d_in[1];
    const float* hb    = (const float*)d_in[2];
    const float* vw    = (const float*)d_in[3];
    const float* vb    = (const float*)d_in[4];
    const float* pww   = (const float*)d_in[5];
    const float* pwb   = (const float*)d_in[6];
    const float* bnw   = (const float*)d_in[7];
    const float* bnb   = (const float*)d_in[8];
    const float* qw    = (const float*)d_in[9];
    const float* qb    = (const float*)d_in[10];
    const float* kw    = (const float*)d_in[11];
    const float* kb    = (const float*)d_in[12];
    const float* vw2   = (const float*)d_in[13];
    const float* vb2   = (const float*)d_in[14];
    const float* gamma = (const float*)d_in[15];

    float* ws = (float*)d_ws;
    const size_t NP = (size_t)Bn * Cc * PLANE;   // 16.7M
    const size_t NQ = (size_t)Bn * CQn * PLANE;  // 2.1M
    float* y_raw  = ws;                        // [NP] f32; live until final
    float* slotB  = ws + NP;                   // hout0/houtT bf16
    float* slotC  = ws + 2 * NP;               // a_buf bf16 -> valT bf16
    float* slotD  = ws + 2 * NP + NP / 2;      // valb bf16
    float* ptr    = ws + 3 * NP;
    ushortT* qbuf = (ushortT*)ptr;             // NQ bf16
    ushortT* kbuf = qbuf + NQ;
    ushortT* qT   = kbuf + NQ;
    ushortT* kT   = qT + NQ;
    float* sums   = (float*)(kT + NQ);         // 256
    float* sumsq  = sums + 256;

    ushortT* a_buf = (ushortT*)slotC;
    ushortT* valT  = (ushortT*)slotC;   // a_buf dead after pw
    ushortT* valb  = (ushortT*)slotD;
    ushortT* hout0 = (ushortT*)slotB;   // bf16 width-attn out
    ushortT* houtT = hout0 + NP;        // bf16 height-attn out (transposed layout)
    float* out  = (float*)d_out;
    float* down = out + NP;

    hipMemsetAsync(sums, 0, 512 * sizeof(float), stream);
    dw_kernel<<<dim3(Bn * Cc * 16), dim3(256), 0, stream>>>(
        x, hw, hb, vw, vb, a_buf);
    pw_mfma_kernel<<<dim3(Bn * 256), dim3(256), 0, stream>>>(
        a_buf, pww, pwb, y_raw, sums, sumsq);
    qkv_mfma_kernel<<<dim3(Bn * 256), dim3(256), 0, stream>>>(
        y_raw, sums, sumsq, bnw, bnb, qw, qb, kw, kb, vw2, vb2,
        qbuf, kbuf, valb);
    transpose_all_kernel<<<dim3(320 * 64), dim3(256), 0, stream>>>(
        qbuf, qT, kbuf, kT, valb, valT);
    attn_kernel<<<dim3(2 * Bn * Hh), dim3(256), 0, stream>>>(
        qbuf, kbuf, valb, hout0, qT, kT, valT, houtT);
    final_kernel<<<dim3(Bn * Cc * 64), dim3(256), 0, stream>>>(
        houtT, hout0, y_raw, sums, sumsq, bnw, bnb, gamma, out, down);
}

// Round 8
// 354.358 us; speedup vs baseline: 1.0314x; 1.0314x over previous
//
#include <hip/hip_runtime.h>
#include <hip/hip_bf16.h>

#define Bn 4
#define Cc 64
#define CQn 8
#define Hh 256
#define Ww 256
#define PLANE 65536

typedef unsigned short ushortT;
typedef __attribute__((ext_vector_type(8))) unsigned short us8;
typedef __attribute__((ext_vector_type(4))) unsigned short us4;
typedef __attribute__((ext_vector_type(8))) __bf16 bf16x8;
typedef __attribute__((ext_vector_type(4))) float f32x4;

__device__ inline ushortT f2bf(float f) {
    __hip_bfloat16 h = __float2bfloat16(f);
    return *(ushortT*)&h;
}
__device__ inline float bf2f(ushortT u) {
    return __uint_as_float((unsigned)u << 16);
}
union BF8U { us8 u; bf16x8 b; uint4 w; };
__device__ inline us8 zero_us8() {
    BF8U z; z.w.x = 0; z.w.y = 0; z.w.z = 0; z.w.w = 0; return z.u;
}

// ---------- Kernel 1a: axial depthwise conv + relu (bf16 out) ----------
// Block 0 also zeroes the stats accumulators (replaces the memset dispatch;
// the dw->pw kernel boundary orders it before pw's atomics).
__global__ __launch_bounds__(256) void dw_kernel(
    const float* __restrict__ x,
    const float* __restrict__ hw, const float* __restrict__ hb,
    const float* __restrict__ vw, const float* __restrict__ vb,
    ushortT* __restrict__ aout,
    float* __restrict__ sums, float* __restrict__ sumsq)
{
    int blk = blockIdx.x;
    int tid = threadIdx.x;
    if (blk == 0) { sums[tid] = 0.f; sumsq[tid] = 0.f; }
    int bc = blk >> 4;
    int ht = blk & 15;
    int h0 = ht * 16;
    int c = bc & 63;
    __shared__ float rows[20][260];
    const float* xp = x + (size_t)bc * PLANE;
    #pragma unroll
    for (int i = 0; i < 20; ++i) {
        int hr = h0 - 2 + i;
        rows[i][tid + 2] = (hr >= 0 && hr < Hh) ? xp[hr * Ww + tid] : 0.f;
    }
    if (tid < 20) {
        rows[tid][0] = 0.f; rows[tid][1] = 0.f;
        rows[tid][258] = 0.f; rows[tid][259] = 0.f;
    }
    __syncthreads();

    float hw0 = hw[c * 5 + 0], hw1 = hw[c * 5 + 1], hw2 = hw[c * 5 + 2],
          hw3 = hw[c * 5 + 3], hw4 = hw[c * 5 + 4];
    float vw0 = vw[c * 5 + 0], vw1 = vw[c * 5 + 1], vw2 = vw[c * 5 + 2],
          vw3 = vw[c * 5 + 3], vw4 = vw[c * 5 + 4];
    float bias = hb[c] + vb[c];

    ushortT* op = aout + (size_t)bc * PLANE + h0 * Ww + tid;
    #pragma unroll
    for (int r = 0; r < 16; ++r) {
        float hs = hw0 * rows[r + 2][tid]     + hw1 * rows[r + 2][tid + 1]
                 + hw2 * rows[r + 2][tid + 2] + hw3 * rows[r + 2][tid + 3]
                 + hw4 * rows[r + 2][tid + 4];
        float vs = vw0 * rows[r][tid + 2]     + vw1 * rows[r + 1][tid + 2]
                 + vw2 * rows[r + 2][tid + 2] + vw3 * rows[r + 3][tid + 2]
                 + vw4 * rows[r + 4][tid + 2];
        float res = hs + vs + bias + rows[r + 2][tid + 2];
        op[r * Ww] = f2bf(fmaxf(res, 0.f));
    }
}

// ---------- Kernel 1b: pointwise 64x64 via MFMA + fused stats partials ----------
// y is stored as bf16 (stats accumulated in f32 pre-rounding).
__global__ __launch_bounds__(256) void pw_mfma_kernel(
    const ushortT* __restrict__ a_bf, const float* __restrict__ pwwf,
    const float* __restrict__ pwb,
    ushortT* __restrict__ y_bf, float* __restrict__ sums, float* __restrict__ sumsq)
{
    int blk = blockIdx.x;
    int b = blk >> 8;
    int t0 = (blk & 255) << 8;
    int tid = threadIdx.x, lane = tid & 63, wv = tid >> 6;
    int half = lane >> 4;
    int col = lane & 15;

    __shared__ ushortT ytile[256 * 74];

    {
        size_t base = (size_t)b * Cc * PLANE + t0 + tid;
        uint* wrow = (uint*)&ytile[tid * 74];
        #pragma unroll
        for (int c = 0; c < Cc; c += 2) {
            ushortT v0 = a_bf[base + (size_t)c * PLANE];
            ushortT v1 = a_bf[base + (size_t)(c + 1) * PLANE];
            wrow[c >> 1] = (uint)v0 | ((uint)v1 << 16);
        }
    }
    __syncthreads();

    int m0 = wv * 16;
    BF8U a0, a1;
    {
        const float* wr = pwwf + (m0 + col) * 64 + half * 8;
        #pragma unroll
        for (int e = 0; e < 8; ++e) {
            a0.u[e] = f2bf(wr[e]);
            a1.u[e] = f2bf(wr[32 + e]);
        }
    }

    float bias[4], s[4], s2[4];
    #pragma unroll
    for (int r = 0; r < 4; ++r) {
        bias[r] = pwb[m0 + half * 4 + r];
        s[r] = 0.f; s2[r] = 0.f;
    }

    const uint* lw = (const uint*)ytile;
    #pragma unroll 4
    for (int t = 0; t < 16; ++t) {
        int rbase = (t * 16 + col) * 37 + half * 4;
        BF8U b0, b1;
        b0.w.x = lw[rbase];      b0.w.y = lw[rbase + 1];
        b0.w.z = lw[rbase + 2];  b0.w.w = lw[rbase + 3];
        b1.w.x = lw[rbase + 16]; b1.w.y = lw[rbase + 17];
        b1.w.z = lw[rbase + 18]; b1.w.w = lw[rbase + 19];
        f32x4 acc = (f32x4){0.f, 0.f, 0.f, 0.f};
        acc = __builtin_amdgcn_mfma_f32_16x16x32_bf16(a0.b, b0.b, acc, 0, 0, 0);
        acc = __builtin_amdgcn_mfma_f32_16x16x32_bf16(a1.b, b1.b, acc, 0, 0, 0);
        int pix = t * 16 + col;
        #pragma unroll
        for (int r = 0; r < 4; ++r) {
            int c = m0 + half * 4 + r;
            float v = acc[r] + bias[r];
            y_bf[(size_t)(b * Cc + c) * PLANE + t0 + pix] = f2bf(v);
            s[r] += v; s2[r] += v * v;
        }
    }
    #pragma unroll
    for (int r = 0; r < 4; ++r) {
        #pragma unroll
        for (int d = 8; d > 0; d >>= 1) {
            s[r]  += __shfl_down(s[r], d, 16);
            s2[r] += __shfl_down(s2[r], d, 16);
        }
    }
    if (col == 0) {
        #pragma unroll
        for (int r = 0; r < 4; ++r) {
            int c = m0 + half * 4 + r;
            atomicAdd(&sums[b * Cc + c], s[r]);
            atomicAdd(&sumsq[b * Cc + c], s2[r]);
        }
    }
}

// ---------- Kernel 4: norm-fold + normalize + qk/val projections via MFMA ----------
// q and k live in one 16-plane-per-batch buffer (planes 0-7 = q, 8-15 = k):
// the projection write is branch-free (single base + per-lane bias).
__global__ __launch_bounds__(256) void qkv_mfma_kernel(
    const ushortT* __restrict__ y_bf,
    const float* __restrict__ sums, const float* __restrict__ sumsq,
    const float* __restrict__ bnw, const float* __restrict__ bnb,
    const float* __restrict__ qwf, const float* __restrict__ qbias,
    const float* __restrict__ kwf, const float* __restrict__ kbias,
    const float* __restrict__ vwf, const float* __restrict__ vbias,
    ushortT* __restrict__ qk, ushortT* __restrict__ val)
{
    int blk = blockIdx.x;
    int b = blk >> 8;
    int t0 = (blk & 255) << 8;
    int tid = threadIdx.x, lane = tid & 63, wv = tid >> 6;
    int half = lane >> 4;
    int col = lane & 15;

    __shared__ ushortT ytile[256 * 74];
    __shared__ float alpha_s[64], beta_s[64];

    if (tid < 64) {
        int c = tid;
        float im[4], e2[4];
        float bm = 0.f, be2 = 0.f;
        #pragma unroll
        for (int bb = 0; bb < 4; ++bb) {
            im[bb] = sums[bb * Cc + c] * (1.f / 65536.f);
            e2[bb] = sumsq[bb * Cc + c] * (1.f / 65536.f);
            bm += im[bb]; be2 += e2[bb];
        }
        bm *= 0.25f; be2 *= 0.25f;
        float rsb = rsqrtf(be2 - bm * bm + 1e-5f);
        float wgt = bnw[c];
        float rsi = rsqrtf(e2[b] - im[b] * im[b] + 1e-5f);
        alpha_s[c] = 0.7f * rsi + 0.3f * rsb * wgt;
        beta_s[c]  = -0.7f * im[b] * rsi - 0.3f * bm * rsb * wgt + 0.3f * bnb[c];
    }
    __syncthreads();

    {
        size_t base = (size_t)b * Cc * PLANE + t0 + tid;
        uint* wrow = (uint*)&ytile[tid * 74];
        #pragma unroll
        for (int c = 0; c < Cc; c += 2) {
            float v0 = bf2f(y_bf[base + (size_t)c * PLANE]);
            float v1 = bf2f(y_bf[base + (size_t)(c + 1) * PLANE]);
            float n0 = alpha_s[c] * v0 + beta_s[c];
            float n1 = alpha_s[c + 1] * v1 + beta_s[c + 1];
            wrow[c >> 1] = (uint)f2bf(n0) | ((uint)f2bf(n1) << 16);
        }
    }
    __syncthreads();

    const uint* lw = (const uint*)ytile;

    {
        // combined q/k projection: output rows 0-7 = q, 8-15 = k
        const float* wr = (col < 8) ? (qwf + col * 64) : (kwf + (col - 8) * 64);
        BF8U a0, a1;
        #pragma unroll
        for (int e = 0; e < 8; ++e) {
            a0.u[e] = f2bf(wr[half * 8 + e]);
            a1.u[e] = f2bf(wr[32 + half * 8 + e]);
        }
        float qkb4[4];
        #pragma unroll
        for (int r = 0; r < 4; ++r) {
            int row = half * 4 + r;
            qkb4[r] = (row < 8) ? qbias[row] : kbias[row - 8];
        }
        #pragma unroll
        for (int i = 0; i < 4; ++i) {
            int t = wv * 4 + i;
            int rbase = (t * 16 + col) * 37 + half * 4;
            BF8U b0, b1;
            b0.w.x = lw[rbase];      b0.w.y = lw[rbase + 1];
            b0.w.z = lw[rbase + 2];  b0.w.w = lw[rbase + 3];
            b1.w.x = lw[rbase + 16]; b1.w.y = lw[rbase + 17];
            b1.w.z = lw[rbase + 18]; b1.w.w = lw[rbase + 19];
            f32x4 acc = (f32x4){0.f, 0.f, 0.f, 0.f};
            acc = __builtin_amdgcn_mfma_f32_16x16x32_bf16(a0.b, b0.b, acc, 0, 0, 0);
            acc = __builtin_amdgcn_mfma_f32_16x16x32_bf16(a1.b, b1.b, acc, 0, 0, 0);
            int pix = t * 16 + col;
            #pragma unroll
            for (int r = 0; r < 4; ++r) {
                int row = half * 4 + r;
                qk[(size_t)(b * 16 + row) * PLANE + t0 + pix] = f2bf(acc[r] + qkb4[r]);
            }
        }
    }

    {
        int m0 = wv * 16;
        BF8U a0, a1;
        {
            const float* wr = vwf + (m0 + col) * 64 + half * 8;
            #pragma unroll
            for (int e = 0; e < 8; ++e) {
                a0.u[e] = f2bf(wr[e]);
                a1.u[e] = f2bf(wr[32 + e]);
            }
        }
        float bias[4];
        #pragma unroll
        for (int r = 0; r < 4; ++r) bias[r] = vbias[m0 + half * 4 + r];
        #pragma unroll 4
        for (int t = 0; t < 16; ++t) {
            int rbase = (t * 16 + col) * 37 + half * 4;
            BF8U b0, b1;
            b0.w.x = lw[rbase];      b0.w.y = lw[rbase + 1];
            b0.w.z = lw[rbase + 2];  b0.w.w = lw[rbase + 3];
            b1.w.x = lw[rbase + 16]; b1.w.y = lw[rbase + 17];
            b1.w.z = lw[rbase + 18]; b1.w.w = lw[rbase + 19];
            f32x4 acc = (f32x4){0.f, 0.f, 0.f, 0.f};
            acc = __builtin_amdgcn_mfma_f32_16x16x32_bf16(a0.b, b0.b, acc, 0, 0, 0);
            acc = __builtin_amdgcn_mfma_f32_16x16x32_bf16(a1.b, b1.b, acc, 0, 0, 0);
            int pix = t * 16 + col;
            #pragma unroll
            for (int r = 0; r < 4; ++r) {
                int c = m0 + half * 4 + r;
                val[(size_t)(b * Cc + c) * PLANE + t0 + pix] = f2bf(acc[r] + bias[r]);
            }
        }
    }
}

// ---------- Kernel 5: merged qk/val plane transpose (one launch) ----------
__global__ __launch_bounds__(256) void transpose_all_kernel(
    const ushortT* __restrict__ qkb, ushortT* __restrict__ qkT,
    const ushortT* __restrict__ vb, ushortT* __restrict__ vT)
{
    int blk = blockIdx.x;
    int plane = blk >> 6;      // 0..319: 64 qk planes, 256 val planes
    int tile = blk & 63;
    const ushortT* src; ushortT* dst;
    if (plane < 64) { src = qkb + (size_t)plane * PLANE;        dst = qkT + (size_t)plane * PLANE; }
    else            { src = vb + (size_t)(plane - 64) * PLANE;  dst = vT + (size_t)(plane - 64) * PLANE; }
    int th = (tile >> 3) * 32;
    int tw = (tile & 7) * 32;
    __shared__ ushortT t[32][34];
    int lw = threadIdx.x & 31;
    int lh = threadIdx.x >> 5;
    #pragma unroll
    for (int i = 0; i < 4; ++i)
        t[lh + 8 * i][lw] = src[(th + lh + 8 * i) * Ww + tw + lw];
    __syncthreads();
    #pragma unroll
    for (int i = 0; i < 4; ++i)
        dst[(tw + lh + 8 * i) * Hh + th + lw] = t[lw][lh + 8 * i];
}

// ---------- Kernel 6: TWO-PASS softmax attention (r7 math, qk merged buffer) ----------
__global__ __launch_bounds__(256) void attn_kernel(
    const ushortT* __restrict__ qk0, const ushortT* __restrict__ v0,
    ushortT* __restrict__ o0,
    const ushortT* __restrict__ qk1, const ushortT* __restrict__ v1,
    ushortT* __restrict__ o1)
{
    int blk = blockIdx.x;
    int sel = blk >> 10;
    const ushortT* __restrict__ qk  = sel ? qk1 : qk0;
    const ushortT* __restrict__ val = sel ? v1 : v0;
    ushortT* __restrict__ outp      = sel ? o1 : o0;
    int bblk = blk & 1023;
    int b = bblk >> 8;
    int r = bblk & 255;
    int tid = threadIdx.x;
    int lane = tid & 63;
    int wv = tid >> 6;
    int col = lane & 15;
    int quad = lane >> 4;

    __shared__ ushortT q_s[256 * 8];        // [j][c] bf16
    __shared__ ushortT k_s[256 * 8];        // [i][c]
    __shared__ ushortT A_lds[4 * 256 * 8];  // [jq][i][8 bf16 j's]
    __shared__ float mhat[256];
    __shared__ float shiftv[256];
    __shared__ float kred[32];

    // ---- val row fragment for this lane: c = wv*16+col, j-slots quad*8..+8 ----
    size_t vbase = (size_t)b * Cc * PLANE + (size_t)r * Ww
                 + (size_t)(wv * 16 + col) * PLANE + quad * 8;
    BF8U afb[2];
    afb[0].u = *(const us8*)(val + vbase);   // slab 0, in flight through phase 1

    // ---- stage q,k ----
    size_t qkbase = (size_t)b * 16 * PLANE + (size_t)r * Ww + tid;
    float qf[8], ka[8];
    {
        BF8U qp, kp;
        #pragma unroll
        for (int c = 0; c < 8; ++c) {
            ushortT qv = qk[qkbase + (size_t)c * PLANE];
            ushortT kv = qk[qkbase + (size_t)(8 + c) * PLANE];
            qp.u[c] = qv; kp.u[c] = kv;
            qf[c] = bf2f(qv);
            ka[c] = fabsf(bf2f(kv));
        }
        *(us8*)&q_s[tid * 8] = qp.u;
        *(us8*)&k_s[tid * 8] = kp.u;
    }
    #pragma unroll
    for (int d = 1; d < 64; d <<= 1)
        #pragma unroll
        for (int c = 0; c < 8; ++c)
            ka[c] = fmaxf(ka[c], __shfl_xor(ka[c], d));
    if (lane == 0)
        #pragma unroll
        for (int c = 0; c < 8; ++c) kred[wv * 8 + c] = ka[c];
    __syncthreads();

    // mhat[j] = sum_c |q_c| * kmax_c (safe upper bound on S row max)
    {
        float mh = 0.f;
        #pragma unroll
        for (int c = 0; c < 8; ++c) {
            float km = fmaxf(fmaxf(kred[c], kred[8 + c]),
                             fmaxf(kred[16 + c], kred[24 + c]));
            mh += fabsf(qf[c]) * km;
        }
        mhat[tid] = mh;
    }
    __syncthreads();

    // ---- phase 1: l[j] via MFMA sweep; shift = mhat + ln(l) ----
    #pragma unroll
    for (int t = 0; t < 4; ++t) {
        int jt = wv * 4 + t;
        BF8U qa; qa.u = zero_us8();
        if (quad == 0) qa.u = *(const us8*)&q_s[(jt * 16 + col) * 8];
        float mh4[4];
        #pragma unroll
        for (int rr = 0; rr < 4; ++rr) mh4[rr] = mhat[jt * 16 + quad * 4 + rr];
        f32x4 ls = (f32x4){0.f, 0.f, 0.f, 0.f};
        for (int it = 0; it < 16; ++it) {
            BF8U kb;
            kb.u = *(const us8*)&k_s[(it * 16 + col) * 8];  // unconditional, qa zeros k>=8
            f32x4 sacc = (f32x4){0.f, 0.f, 0.f, 0.f};
            sacc = __builtin_amdgcn_mfma_f32_16x16x32_bf16(qa.b, kb.b, sacc, 0, 0, 0);
            #pragma unroll
            for (int rr = 0; rr < 4; ++rr)
                ls[rr] += __expf(sacc[rr] - mh4[rr]);
        }
        #pragma unroll
        for (int d = 1; d < 16; d <<= 1)
            #pragma unroll
            for (int rr = 0; rr < 4; ++rr)
                ls[rr] += __shfl_xor(ls[rr], d);
        if (col == 0)
            #pragma unroll
            for (int rr = 0; rr < 4; ++rr)
                shiftv[jt * 16 + quad * 4 + rr] = mh4[rr] + __logf(ls[rr]);
    }
    __syncthreads();

    // ---- phase 2: per slab {E -> A_lds; barrier; AV; barrier} ----
    BF8U kc[4];
    #pragma unroll
    for (int i = 0; i < 4; ++i)
        kc[i].u = *(const us8*)&k_s[((wv * 4 + i) * 16 + col) * 8];
    f32x4 acc[16];
    #pragma unroll
    for (int t = 0; t < 16; ++t) acc[t] = (f32x4){0.f, 0.f, 0.f, 0.f};

    #pragma unroll
    for (int ks = 0; ks < 8; ++ks) {
        if (ks < 7)   // prefetch next val slab; hidden under E + barrier
            afb[(ks + 1) & 1].u = *(const us8*)(val + vbase + (ks + 1) * 32);
        #pragma unroll
        for (int jj2 = 0; jj2 < 2; ++jj2) {
            int jt = ks * 2 + jj2;
            BF8U qa; qa.u = zero_us8();
            if (quad == 0) qa.u = *(const us8*)&q_s[(jt * 16 + col) * 8];
            float sh4[4];
            #pragma unroll
            for (int rr = 0; rr < 4; ++rr) sh4[rr] = shiftv[jt * 16 + quad * 4 + rr];
            #pragma unroll
            for (int i = 0; i < 4; ++i) {
                f32x4 sacc = (f32x4){0.f, 0.f, 0.f, 0.f};
                sacc = __builtin_amdgcn_mfma_f32_16x16x32_bf16(qa.b, kc[i].b, sacc, 0, 0, 0);
                us4 pk;
                #pragma unroll
                for (int rr = 0; rr < 4; ++rr)
                    pk[rr] = f2bf(__expf(sacc[rr] - sh4[rr]));
                int irow = (wv * 4 + i) * 16 + col;
                int jq = jj2 * 2 + (quad >> 1);
                *(us4*)&A_lds[(jq * 256 + irow) * 8 + (quad & 1) * 4] = pk;
            }
        }
        __syncthreads();
        #pragma unroll
        for (int t = 0; t < 16; ++t) {
            BF8U bfr;
            bfr.u = *(const us8*)&A_lds[(quad * 256 + t * 16 + col) * 8];
            acc[t] = __builtin_amdgcn_mfma_f32_16x16x32_bf16(afb[ks & 1].b, bfr.b, acc[t], 0, 0, 0);
        }
        __syncthreads();
    }

    // store: C/D layout col=i, row c=quad*4+rr; wave wv owns c-tile wv
    size_t obase = (size_t)b * Cc * PLANE + (size_t)r * Ww;
    #pragma unroll
    for (int t = 0; t < 16; ++t) {
        int i = t * 16 + col;
        #pragma unroll
        for (int rr = 0; rr < 4; ++rr) {
            int c = wv * 16 + quad * 4 + rr;
            outp[obase + (size_t)c * PLANE + i] = f2bf(acc[t][rr]);
        }
    }
}

// ---------- Kernel 7: combine + residual + 2x2 maxpool ----------
__global__ __launch_bounds__(256) void final_kernel(
    const ushortT* __restrict__ houtT, const ushortT* __restrict__ hout0,
    const ushortT* __restrict__ y_bf,
    const float* __restrict__ sums, const float* __restrict__ sumsq,
    const float* __restrict__ bnw, const float* __restrict__ bnb,
    const float* __restrict__ gamma,
    float* __restrict__ out, float* __restrict__ down)
{
    int blk = blockIdx.x;
    int tile = blk & 63;
    int bc = blk >> 6;
    int b = bc >> 6;
    int c = bc & 63;
    int th = (tile >> 3) * 32;
    int tw = (tile & 7) * 32;

    float im[4], e2[4];
    float bm = 0.f, be2 = 0.f;
    #pragma unroll
    for (int bb = 0; bb < 4; ++bb) {
        im[bb] = sums[bb * Cc + c] * (1.f / 65536.f);
        e2[bb] = sumsq[bb * Cc + c] * (1.f / 65536.f);
        bm += im[bb]; be2 += e2[bb];
    }
    bm *= 0.25f; be2 *= 0.25f;
    float rsb = rsqrtf(be2 - bm * bm + 1e-5f);
    float wgt = bnw[c];
    float rsi = rsqrtf(e2[b] - im[b] * im[b] + 1e-5f);
    float al = 0.7f * rsi + 0.3f * rsb * wgt;
    float bt = -0.7f * im[b] * rsi - 0.3f * bm * rsb * wgt + 0.3f * bnb[c];

    __shared__ float t[32][33];
    const ushortT* hT = houtT + (size_t)bc * PLANE;
    {
        int ww = threadIdx.x >> 3;
        int hh = (threadIdx.x & 7) * 4;
        us4 v4 = *(const us4*)(hT + (size_t)(tw + ww) * Hh + th + hh);
        t[hh + 0][ww] = __uint_as_float((unsigned)v4[0] << 16);
        t[hh + 1][ww] = __uint_as_float((unsigned)v4[1] << 16);
        t[hh + 2][ww] = __uint_as_float((unsigned)v4[2] << 16);
        t[hh + 3][ww] = __uint_as_float((unsigned)v4[3] << 16);
    }
    __syncthreads();
    float g = gamma[0];
    int qw_ = threadIdx.x & 15;
    int qh_ = threadIdx.x >> 4;
    const ushortT* yb = y_bf + (size_t)bc * PLANE;
    const ushortT* hb = hout0 + (size_t)bc * PLANE;
    float* ob = out + (size_t)bc * PLANE;
    float mx = -1e30f;
    float2 res[2];
    #pragma unroll
    for (int i = 0; i < 2; ++i) {
        int hh = 2 * qh_ + i;
        int off = (th + hh) * Ww + tw + 2 * qw_;
        uint hv = *(const uint*)(hb + off);
        uint yv = *(const uint*)(yb + off);
        float y0 = al * bf2f((ushortT)(yv & 0xffff)) + bt;
        float y1 = al * bf2f((ushortT)(yv >> 16))   + bt;
        float o0 = g * (t[hh][2 * qw_]     + bf2f((ushortT)(hv & 0xffff))) + y0;
        float o1 = g * (t[hh][2 * qw_ + 1] + bf2f((ushortT)(hv >> 16)))   + y1;
        res[i] = make_float2(o0, o1);
        mx = fmaxf(mx, fmaxf(o0, o1));
    }
    #pragma unroll
    for (int i = 0; i < 2; ++i) {
        int off = (th + 2 * qh_ + i) * Ww + tw + 2 * qw_;
        *(float2*)(ob + off) = res[i];
    }
    down[(size_t)bc * 16384 + (th / 2 + qh_) * 128 + tw / 2 + qw_] = mx;
}

extern "C" void kernel_launch(void* const* d_in, const int* in_sizes, int n_in,
                              void* d_out, int out_size, void* d_ws, size_t ws_size,
                              hipStream_t stream)
{
    const float* x     = (const float*)d_in[0];
    const float* hw    = (const float*)d_in[1];
    const float* hb    = (const float*)d_in[2];
    const float* vw    = (const float*)d_in[3];
    const float* vb    = (const float*)d_in[4];
    const float* pww   = (const float*)d_in[5];
    const float* pwb   = (const float*)d_in[6];
    const float* bnw   = (const float*)d_in[7];
    const float* bnb   = (const float*)d_in[8];
    const float* qw    = (const float*)d_in[9];
    const float* qb    = (const float*)d_in[10];
    const float* kw    = (const float*)d_in[11];
    const float* kb    = (const float*)d_in[12];
    const float* vw2   = (const float*)d_in[13];
    const float* vb2   = (const float*)d_in[14];
    const float* gamma = (const float*)d_in[15];

    float* ws = (float*)d_ws;
    const size_t NP = (size_t)Bn * Cc * PLANE;   // 16.7M elements
    const size_t NQ = (size_t)Bn * CQn * PLANE;  // 2.1M
    ushortT* y_bf = (ushortT*)ws;              // NP bf16 (uses half the old f32 slot)
    float* slotB  = ws + NP;                   // hout0/houtT bf16
    float* slotC  = ws + 2 * NP;               // a_buf bf16 -> valT bf16
    float* slotD  = ws + 2 * NP + NP / 2;      // valb bf16
    float* ptr    = ws + 3 * NP;
    ushortT* qkbuf = (ushortT*)ptr;            // 2*NQ bf16 (16 planes x 4 batches)
    ushortT* qkT   = qkbuf + 2 * NQ;           // 2*NQ
    float* sums   = (float*)(qkT + 2 * NQ);    // 256
    float* sumsq  = sums + 256;

    ushortT* a_buf = (ushortT*)slotC;
    ushortT* valT  = (ushortT*)slotC;   // a_buf dead after pw
    ushortT* valb  = (ushortT*)slotD;
    ushortT* hout0 = (ushortT*)slotB;   // bf16 width-attn out
    ushortT* houtT = hout0 + NP;        // bf16 height-attn out (transposed layout)
    float* out  = (float*)d_out;
    float* down = out + NP;

    dw_kernel<<<dim3(Bn * Cc * 16), dim3(256), 0, stream>>>(
        x, hw, hb, vw, vb, a_buf, sums, sumsq);
    pw_mfma_kernel<<<dim3(Bn * 256), dim3(256), 0, stream>>>(
        a_buf, pww, pwb, y_bf, sums, sumsq);
    qkv_mfma_kernel<<<dim3(Bn * 256), dim3(256), 0, stream>>>(
        y_bf, sums, sumsq, bnw, bnb, qw, qb, kw, kb, vw2, vb2,
        qkbuf, valb);
    transpose_all_kernel<<<dim3(320 * 64), dim3(256), 0, stream>>>(
        qkbuf, qkT, valb, valT);
    attn_kernel<<<dim3(2 * Bn * Hh), dim3(256), 0, stream>>>(
        qkbuf, valb, hout0, qkT, valT, houtT);
    final_kernel<<<dim3(Bn * Cc * 64), dim3(256), 0, stream>>>(
        houtT, hout0, y_bf, sums, sumsq, bnw, bnb, gamma, out, down);
}